// Round 11
// baseline (493.285 us; speedup 1.0000x reference)
//
#include <hip/hip_runtime.h>
#include <stdint.h>

typedef __bf16 bf16_t;
typedef __bf16 bf16x8 __attribute__((ext_vector_type(8)));
typedef float f32x16 __attribute__((ext_vector_type(16)));

// async global->LDS, 16B per lane; HW dest = wave-uniform base + lane*16
__device__ __forceinline__ void gload_lds16(const void* g, void* l) {
  __builtin_amdgcn_global_load_lds(
      (const __attribute__((address_space(1))) uint32_t*)g,
      (__attribute__((address_space(3))) uint32_t*)l, 16, 0, 0);
}

// ---------------- fused cast f32 -> bf16 for 3 buffers ----------------
__global__ void cast3_f32_bf16(const float* __restrict__ a, bf16_t* __restrict__ ao, int n4a,
                               const float* __restrict__ b, bf16_t* __restrict__ bo, int n4b,
                               const float* __restrict__ c, bf16_t* __restrict__ co, int n4c) {
  int i = blockIdx.x * blockDim.x + threadIdx.x;
  int stride = gridDim.x * blockDim.x;
  int total = n4a + n4b + n4c;
  for (int idx = i; idx < total; idx += stride) {
    const float* src; bf16_t* dst; int j = idx;
    if (j < n4a) { src = a; dst = ao; }
    else if ((j -= n4a) < n4b) { src = b; dst = bo; }
    else { j -= n4b; src = c; dst = co; }
    float4 v = reinterpret_cast<const float4*>(src)[j];
    union { bf16_t b[4]; uint2 u; } pk;
    pk.b[0] = (bf16_t)v.x; pk.b[1] = (bf16_t)v.y;
    pk.b[2] = (bf16_t)v.z; pk.b[3] = (bf16_t)v.w;
    reinterpret_cast<uint2*>(dst)[j] = pk.u;
  }
}

// ------ fat-wave GEMM: C[M][N] = A[M][K]*B[N][K]^T (+bias) ------
// BM=BN=256, BK=32, K=1024 (NT=32). 256 thr = 4 waves (2x2), wave tile
// 128x128 = 4x4 frags of mfma_f32_32x32x16_bf16 (acc 16 x f32x16 = 256 VGPR,
// 1 wave/SIMD). LDS reads drop to 64KB/CU/tile (A-frag reuse over 4 B-frags)
// and MFMA count halves vs 16x16 (higher ceiling: 2495 TF m119).
// 4-slot LDS ring (128KB), staged 3 ahead. Per tile (ONE barrier):
//   STAGE(t+3) 8 gloads | RD(t+1) 16 ds_reads (slot landed: gated LAST tile
//   pre-barrier) | 32 MFMA (regs from last tile; reads return underneath)
//   | lgkmcnt(0) | vmcnt(8) -> slot t+2 landed chip-wide BEFORE the barrier
//   (so every wave may read it next tile) | s_barrier
// A/B k-mapping (lane l: row=l&31, k=(l>>5)*8+e per kstep): correctness needs
// only A/B-consistency (verified principle from the working 16x16x32 kernel).
// C/D 32x32 map (HW-verified m74/m101): col=lane&31, row=(reg&3)+8*(reg>>2)
// +4*(lane>>5). Swizzle: LDS[r][c16]=G[r][c16^((r>>1)&3)] both sides (0
// conflicts, r4-verified). Grid: XCD x owns bx slab [x*8,x*8+8), bx-fast.
template <bool BF16_OUT>
__global__ __launch_bounds__(256, 1)
void gemm_fat(const bf16_t* __restrict__ A, const bf16_t* __restrict__ B,
              void* __restrict__ Cout, const float* __restrict__ bias, int N) {
  constexpr int K = 1024, NT = 32;
  __shared__ bf16_t Al[4][256 * 32];  // 4 x 16KB
  __shared__ bf16_t Bl[4][256 * 32];  // 4 x 16KB

  const int tid = threadIdx.x;
  const int l = tid & 63, w = tid >> 6;
  const int wm = w >> 1, wn = w & 1;

  const int bid = blockIdx.x;
  const int xcd = bid & 7, idx = bid >> 3;
  const int bx = xcd * 8 + (idx & 7);  // nbx = 64 (M = 16384)
  const int by = idx >> 3;
  const int m0 = bx * 256, n0 = by * 256;

  // staging (256 thr, 4KB/issue = 64 rows): thread t: row = t>>2, lds chunk
  // t&3, global chunk = (t&3) ^ ((row>>1)&3) = (t&3)^((t>>3)&3)
  const int ra = tid >> 2;
  const int ca = ((tid & 3) ^ ((tid >> 3) & 3)) * 8;
  const bf16_t* pA0 = A + (size_t)(m0 +   0 + ra) * K + ca;
  const bf16_t* pA1 = A + (size_t)(m0 +  64 + ra) * K + ca;
  const bf16_t* pA2 = A + (size_t)(m0 + 128 + ra) * K + ca;
  const bf16_t* pA3 = A + (size_t)(m0 + 192 + ra) * K + ca;
  const bf16_t* pB0 = B + (size_t)(n0 +   0 + ra) * K + ca;
  const bf16_t* pB1 = B + (size_t)(n0 +  64 + ra) * K + ca;
  const bf16_t* pB2 = B + (size_t)(n0 + 128 + ra) * K + ca;
  const bf16_t* pB3 = B + (size_t)(n0 + 192 + ra) * K + ca;
  const int wb = tid * 8;  // thread's 16B within a 4KB issue

#define STAGE(t_, s_) do { const int kt_ = (t_) * 32;     \
    gload_lds16(pA0 + kt_, &Al[s_][0 * 2048 + wb]);       \
    gload_lds16(pA1 + kt_, &Al[s_][1 * 2048 + wb]);       \
    gload_lds16(pA2 + kt_, &Al[s_][2 * 2048 + wb]);       \
    gload_lds16(pA3 + kt_, &Al[s_][3 * 2048 + wb]);       \
    gload_lds16(pB0 + kt_, &Bl[s_][0 * 2048 + wb]);       \
    gload_lds16(pB1 + kt_, &Bl[s_][1 * 2048 + wb]);       \
    gload_lds16(pB2 + kt_, &Bl[s_][2 * 2048 + wb]);       \
    gload_lds16(pB3 + kt_, &Bl[s_][3 * 2048 + wb]); } while (0)

  // fragment reads: row = base + fr*32 + (l&31) -> (row>>1)&3 = (l>>1)&3
  const int abase = (wm * 128 + (l & 31)) * 32;
  const int bbase = (wn * 128 + (l & 31)) * 32;
  const int ck0 = (((l >> 5) + 0) ^ ((l >> 1) & 3)) * 8;  // kstep 0
  const int ck1 = (((l >> 5) + 2) ^ ((l >> 1) & 3)) * 8;  // kstep 1

#define RD(af_, bf_, s_) do {                                                  \
    const bf16_t* As_ = Al[s_]; const bf16_t* Bs_ = Bl[s_];                    \
    _Pragma("unroll") for (int fr = 0; fr < 4; ++fr) {                         \
      af_[fr][0] = *reinterpret_cast<const bf16x8*>(&As_[abase + fr * 1024 + ck0]); \
      af_[fr][1] = *reinterpret_cast<const bf16x8*>(&As_[abase + fr * 1024 + ck1]); \
    }                                                                          \
    _Pragma("unroll") for (int fc = 0; fc < 4; ++fc) {                         \
      bf_[fc][0] = *reinterpret_cast<const bf16x8*>(&Bs_[bbase + fc * 1024 + ck0]); \
      bf_[fc][1] = *reinterpret_cast<const bf16x8*>(&Bs_[bbase + fc * 1024 + ck1]); \
    } } while (0)

#define MM32(af_, bf_)                                                         \
    __builtin_amdgcn_s_setprio(1);                                             \
    _Pragma("unroll") for (int ks = 0; ks < 2; ++ks)                           \
    _Pragma("unroll") for (int fr = 0; fr < 4; ++fr)                           \
    _Pragma("unroll") for (int fc = 0; fc < 4; ++fc)                           \
      acc[fr][fc] = __builtin_amdgcn_mfma_f32_32x32x16_bf16(                   \
          af_[fr][ks], bf_[fc][ks], acc[fr][fc], 0, 0, 0);                     \
    __builtin_amdgcn_s_setprio(0);

#define BARF() do { asm volatile("" ::: "memory");  \
    __builtin_amdgcn_s_barrier();                   \
    asm volatile("" ::: "memory"); } while (0)

#define TILE(t_, CA, CB, NA, NB) do {                                      \
    if ((t_) + 3 < NT) STAGE((t_) + 3, ((t_) + 3) & 3);                    \
    if ((t_) + 1 < NT) RD(NA, NB, ((t_) + 1) & 3);                         \
    MM32(CA, CB);                                                          \
    asm volatile("s_waitcnt lgkmcnt(0)" ::: "memory");                     \
    if ((t_) < NT - 3)       asm volatile("s_waitcnt vmcnt(8)" ::: "memory"); \
    else if ((t_) == NT - 3) asm volatile("s_waitcnt vmcnt(0)" ::: "memory"); \
    BARF();                                                                \
  } while (0)

  f32x16 acc[4][4] = {};
  bf16x8 afA[4][2], bfA[4][2], afB[4][2], bfB[4][2];

  // prologue: stage slots 0,1,2 (24 loads); slot0+1 landed (allow slot2's 8)
  STAGE(0, 0); STAGE(1, 1); STAGE(2, 2);
  asm volatile("s_waitcnt vmcnt(8)" ::: "memory");
  BARF();
  RD(afA, bfA, 0);

  for (int tt = 0; tt < NT; tt += 2) {
    TILE(tt, afA, bfA, afB, bfB);
    TILE(tt + 1, afB, bfB, afA, bfA);
  }
#undef STAGE
#undef RD
#undef MM32
#undef BARF
#undef TILE

  // ---- epilogue: 32x32 C/D map col=lane&31, row=(reg&3)+8*(reg>>2)+4*(l>>5)
  const int rbase = m0 + wm * 128 + 4 * (l >> 5);
  const int cbase = n0 + wn * 128 + (l & 31);
  if (BF16_OUT) {
    bf16_t* C = (bf16_t*)Cout;
#pragma unroll
    for (int fr = 0; fr < 4; ++fr)
#pragma unroll
      for (int fc = 0; fc < 4; ++fc)
#pragma unroll
        for (int rg = 0; rg < 16; ++rg) {
          int row = rbase + fr * 32 + (rg & 3) + 8 * (rg >> 2);
          C[(size_t)row * N + (cbase + fc * 32)] = (bf16_t)acc[fr][fc][rg];
        }
  } else {
    float* C = (float*)Cout;
#pragma unroll
    for (int fr = 0; fr < 4; ++fr)
#pragma unroll
      for (int fc = 0; fc < 4; ++fc)
#pragma unroll
        for (int rg = 0; rg < 16; ++rg) {
          int row = rbase + fr * 32 + (rg & 3) + 8 * (rg >> 2);
          int col = cbase + fc * 32;
          C[(size_t)row * N + col] = acc[fr][fc][rg] + bias[col];
        }
  }
}

// ---------------- per-token head-attention ----------------
__global__ __launch_bounds__(256)
void attn_heads(const bf16_t* __restrict__ qkv, bf16_t* __restrict__ out) {
  __shared__ float s[4][3072];
  const int w = threadIdx.x >> 6, l = threadIdx.x & 63;
  const size_t t = (size_t)blockIdx.x * 4 + w;
  const bf16_t* src = qkv + t * 3072;
#pragma unroll
  for (int i = 0; i < 6; ++i) {
    int f = (i * 64 + l) * 8;
    bf16x8 v = *reinterpret_cast<const bf16x8*>(&src[f]);
#pragma unroll
    for (int jj = 0; jj < 8; ++jj) s[w][f + jj] = (float)v[jj];
  }
  __syncthreads();

  const int h = l >> 2, ss = l & 3;
  float qr[16];
  const float* qb = &s[w][h * 192 + ss * 16];
#pragma unroll
  for (int d = 0; d < 16; ++d) qr[d] = qb[d];

  float sc[16];
#pragma unroll
  for (int g = 0; g < 16; ++g) {
    const float* kk = &s[w][g * 192 + 64 + ss * 16];
    float p = 0.f;
#pragma unroll
    for (int d = 0; d < 16; ++d) p += qr[d] * kk[d];
    p += __shfl_xor(p, 1);
    p += __shfl_xor(p, 2);
    sc[g] = p * 0.125f;
  }
  float m = sc[0];
#pragma unroll
  for (int g = 1; g < 16; ++g) m = fmaxf(m, sc[g]);
  float sum = 0.f;
#pragma unroll
  for (int g = 0; g < 16; ++g) { sc[g] = __expf(sc[g] - m); sum += sc[g]; }
  float inv = 1.f / sum;

  float o[16] = {};
#pragma unroll
  for (int g = 0; g < 16; ++g) {
    float a = sc[g] * inv;
    const float* vv = &s[w][g * 192 + 128 + ss * 16];
#pragma unroll
    for (int d = 0; d < 16; ++d) o[d] += a * vv[d];
  }
  union { bf16_t b[16]; uint4 u[2]; } pk;
#pragma unroll
  for (int d = 0; d < 16; ++d) pk.b[d] = (bf16_t)o[d];
  uint4* dst = reinterpret_cast<uint4*>(out + t * 1024 + h * 64 + ss * 16);
  dst[0] = pk.u[0];
  dst[1] = pk.u[1];
}

// ---------------- launch ----------------
extern "C" void kernel_launch(void* const* d_in, const int* in_sizes, int n_in,
                              void* d_out, int out_size, void* d_ws, size_t ws_size,
                              hipStream_t stream) {
  const float* x     = (const float*)d_in[0];  // [8,2048,1024]
  const float* Wqkv  = (const float*)d_in[1];  // [3072,1024]
  const float* Wproj = (const float*)d_in[2];  // [1024,1024]
  const float* bproj = (const float*)d_in[3];  // [1024]
  float* out = (float*)d_out;

  const int M = 8 * 2048;   // 16384 tokens -> 64 bx blocks of 256
  const int DM = 1024;
  const int F = 3072;

  char* ws = (char*)d_ws;
  bf16_t* xb     = (bf16_t*)ws;  ws += (size_t)M * DM * 2;
  bf16_t* wqkvb  = (bf16_t*)ws;  ws += (size_t)F * DM * 2;
  bf16_t* wprojb = (bf16_t*)ws;  ws += (size_t)DM * DM * 2;
  bf16_t* qkvb   = (bf16_t*)ws;  ws += (size_t)M * F * 2;
  bf16_t* attnb  = (bf16_t*)ws;

  cast3_f32_bf16<<<2048, 256, 0, stream>>>(x, xb, M * DM / 4,
                                           Wqkv, wqkvb, F * DM / 4,
                                           Wproj, wprojb, DM * DM / 4);

  // GEMM1: [16384,1024] x [3072,1024]^T -> bf16 [16384,3072]
  gemm_fat<true><<<(M / 256) * (F / 256), 256, 0, stream>>>(
      xb, wqkvb, (void*)qkvb, nullptr, F);

  attn_heads<<<M / 4, 256, 0, stream>>>(qkvb, attnb);

  // GEMM2: [16384,1024] x [1024,1024]^T -> f32 [16384,1024] + bias
  gemm_fat<false><<<(M / 256) * (DM / 256), 256, 0, stream>>>(
      attnb, wprojb, (void*)out, bproj, DM);
}

// Round 12
// 219.422 us; speedup vs baseline: 2.2481x; 2.2481x over previous
//
#include <hip/hip_runtime.h>
#include <stdint.h>

typedef __bf16 bf16_t;
typedef __bf16 bf16x8 __attribute__((ext_vector_type(8)));
typedef float f32x4 __attribute__((ext_vector_type(4)));

// async global->LDS, 16B per lane; HW dest = wave-uniform base + lane*16
__device__ __forceinline__ void gload_lds16(const void* g, void* l) {
  __builtin_amdgcn_global_load_lds(
      (const __attribute__((address_space(1))) uint32_t*)g,
      (__attribute__((address_space(3))) uint32_t*)l, 16, 0, 0);
}

// ---------------- fused cast f32 -> bf16 for 3 buffers ----------------
__global__ void cast3_f32_bf16(const float* __restrict__ a, bf16_t* __restrict__ ao, int n4a,
                               const float* __restrict__ b, bf16_t* __restrict__ bo, int n4b,
                               const float* __restrict__ c, bf16_t* __restrict__ co, int n4c) {
  int i = blockIdx.x * blockDim.x + threadIdx.x;
  int stride = gridDim.x * blockDim.x;
  int total = n4a + n4b + n4c;
  for (int idx = i; idx < total; idx += stride) {
    const float* src; bf16_t* dst; int j = idx;
    if (j < n4a) { src = a; dst = ao; }
    else if ((j -= n4a) < n4b) { src = b; dst = bo; }
    else { j -= n4b; src = c; dst = co; }
    float4 v = reinterpret_cast<const float4*>(src)[j];
    union { bf16_t b[4]; uint2 u; } pk;
    pk.b[0] = (bf16_t)v.x; pk.b[1] = (bf16_t)v.y;
    pk.b[2] = (bf16_t)v.z; pk.b[3] = (bf16_t)v.w;
    reinterpret_cast<uint2*>(dst)[j] = pk.u;
  }
}

// ---- 3-block/CU 8-phase GEMM: C[M][N] = A[M][K]*B[N][K]^T (+bias) ----
// BM=256 BN=128 BK=32, K=1024 (NT=32 tiles, NI=16 iters of 2 tiles).
// 256 thr = 4 waves (2M x 2N), wave tile 128x64 (verified frag geometry).
// LDS: [2 dbuf][2 half] x (A 128x32=8KB + B 64x32=4KB) = 48KB -> 3 blocks/CU.
// Independent co-resident blocks de-phase -> one block's MFMA overlaps
// another's LDS reads (the 1-block lockstep capped MfmaUtil at ~36%).
// Phase (ONE barrier each): reads {6,2,4,0} | stage {2,2,1,1,...} gloads |
//   8-MFMA quadrant (setprio) | [vmcnt gate @P4/P8] | s_barrier.
// vmcnt(2) at P4/P8: 8 outstanding, oldest 6 = next dbuf's data; vmcnt(0)
// only last-iter P4. Overwrite audit: every LDS region staged in phase p was
// last ds_read in a phase < p whose MFMA (data-dep) completed pre-barrier.
// Swizzle: LDS[r][c16]=G[r][c16^((r>>1)&3)] both sides (r4-verified 0 conf).
// Grid: XCD x owns bx slab [x*8,x*8+8) (A-slab 4MB = its L2), bx-fast.
template <bool BF16_OUT>
__global__ __launch_bounds__(256, 2)
void gemm_3b(const bf16_t* __restrict__ A, const bf16_t* __restrict__ B,
             void* __restrict__ Cout, const float* __restrict__ bias, int N) {
  constexpr int K = 1024, NI = 16;
  __shared__ bf16_t Al[2][2][128 * 32];  // 2dbuf x 2half x 8KB
  __shared__ bf16_t Bl[2][2][64 * 32];   // 2dbuf x 2half x 4KB

  const int tid = threadIdx.x;
  const int l = tid & 63, w = tid >> 6;
  const int wm = w >> 1, wn = w & 1;

  const int bid = blockIdx.x;
  const int xcd = bid & 7, idx = bid >> 3;
  const int bx = xcd * 8 + (idx & 7);  // nbx = 64 (M = 16384)
  const int by = idx >> 3;
  const int m0 = bx * 256, n0 = by * 128;

  // staging: thread t: row = t>>2 (64 rows/issue), lds chunk t&3,
  // global chunk = (t&3) ^ ((row>>1)&3) = (t&3)^((t>>3)&3)
  const int srow = tid >> 2;
  const int sca = ((tid & 3) ^ ((tid >> 3) & 3)) * 8;
  const bf16_t* pA = A + (size_t)(m0 + srow) * K + sca;
  const bf16_t* pB = B + (size_t)(n0 + srow) * K + sca;

#define ST_A(t_, d_, h_) do {                                                    \
    gload_lds16(pA + (size_t)((h_) * 128) * K + (t_) * 32, &Al[d_][h_][tid * 8]); \
    gload_lds16(pA + (size_t)((h_) * 128 + 64) * K + (t_) * 32,                  \
                &Al[d_][h_][2048 + tid * 8]); } while (0)
#define ST_B(t_, d_, h_) \
    gload_lds16(pB + (size_t)((h_) * 64) * K + (t_) * 32, &Bl[d_][h_][tid * 8])

  // fragment reads: within-half row = (l&15) + f*16 -> (row>>1)&3 = (l>>1)&3
  const int arow = (l & 15) * 32;
  const int ck = ((l >> 4) ^ ((l >> 1) & 3)) * 8;  // swizzled k-chunk (elems)

#define RDA(dst, base, i0) do {                                                  \
    _Pragma("unroll") for (int i = 0; i < 4; ++i)                                \
      dst[i] = *reinterpret_cast<const bf16x8*>(&base[arow + ((i0) + i) * 512 + ck]); \
  } while (0)
#define RDB(dst, base, j0) do {                                                  \
    _Pragma("unroll") for (int j = 0; j < 2; ++j)                                \
      dst[j] = *reinterpret_cast<const bf16x8*>(&base[arow + ((j0) + j) * 512 + ck]); \
  } while (0)

#define MM8(afp, bfp, I0, J0)                                                    \
    __builtin_amdgcn_s_setprio(1);                                               \
    _Pragma("unroll") for (int i = 0; i < 4; ++i)                                \
    _Pragma("unroll") for (int j = 0; j < 2; ++j)                                \
      acc[(I0) + i][(J0) + j] = __builtin_amdgcn_mfma_f32_16x16x32_bf16(         \
          afp[i], bfp[j], acc[(I0) + i][(J0) + j], 0, 0, 0);                     \
    __builtin_amdgcn_s_setprio(0);

#define BARF() do { asm volatile("" ::: "memory");  \
    __builtin_amdgcn_s_barrier();                   \
    asm volatile("" ::: "memory"); } while (0)

  f32x4 acc[8][4] = {};
  bf16x8 aflo[4], afhi[4], bf01[2], bf23[2];

  // prologue: tile0 full (A:4 + B:2 gloads) + tile1 B (2); drain oldest 6
  ST_A(0, 0, 0); ST_A(0, 0, 1); ST_B(0, 0, 0); ST_B(0, 0, 1);
  ST_B(1, 1, 0); ST_B(1, 1, 1);
  asm volatile("s_waitcnt vmcnt(2)" ::: "memory");
  BARF();

  for (int it = 0; it < NI; ++it) {
    const bool last = (it == NI - 1);
    const int ta = 2 * it, tb = ta + 1;
    const bf16_t* A0 = &Al[0][wm][0];
    const bf16_t* B0 = &Bl[0][wn][0];
    const bf16_t* A1 = &Al[1][wm][0];
    const bf16_t* B1 = &Bl[1][wn][0];

    // ---- P1 (d0): rd bf01+aflo | stage A(tb)->d1 h0 | Q1 ----
    RDB(bf01, B0, 0); RDA(aflo, A0, 0);
    ST_A(tb, 1, 0);
    MM8(aflo, bf01, 0, 0);
    BARF();
    // ---- P2: rd bf23 | stage A(tb)->d1 h1 | Q2 ----
    RDB(bf23, B0, 2);
    ST_A(tb, 1, 1);
    MM8(aflo, bf23, 0, 2);
    BARF();
    // ---- P3: rd afhi | stage B(ta+2)->d0 h0 | Q3 ----
    RDA(afhi, A0, 4);
    if (!last) ST_B(ta + 2, 0, 0);
    MM8(afhi, bf01, 4, 0);
    BARF();
    // ---- P4: stage B(ta+2)->d0 h1 | Q4 | gate d1 ----
    if (!last) ST_B(ta + 2, 0, 1);
    MM8(afhi, bf23, 4, 2);
    if (last) asm volatile("s_waitcnt vmcnt(0)" ::: "memory");
    else      asm volatile("s_waitcnt vmcnt(2)" ::: "memory");
    BARF();

    // ---- P5 (d1): rd bf01+aflo | stage A(ta+2)->d0 h0 | Q1 ----
    RDB(bf01, B1, 0); RDA(aflo, A1, 0);
    if (!last) ST_A(ta + 2, 0, 0);
    MM8(aflo, bf01, 0, 0);
    BARF();
    // ---- P6: rd bf23 | stage A(ta+2)->d0 h1 | Q2 ----
    RDB(bf23, B1, 2);
    if (!last) ST_A(ta + 2, 0, 1);
    MM8(aflo, bf23, 0, 2);
    BARF();
    // ---- P7: rd afhi | stage B(tb+2)->d1 h0 | Q3 ----
    RDA(afhi, A1, 4);
    if (!last) ST_B(tb + 2, 1, 0);
    MM8(afhi, bf01, 4, 0);
    BARF();
    // ---- P8: stage B(tb+2)->d1 h1 | Q4 | gate d0(ta+2) ----
    if (!last) ST_B(tb + 2, 1, 1);
    MM8(afhi, bf23, 4, 2);
    if (!last) asm volatile("s_waitcnt vmcnt(2)" ::: "memory");
    BARF();
  }
#undef ST_A
#undef ST_B
#undef RDA
#undef RDB
#undef MM8
#undef BARF

  // ---- epilogue: C/D layout col = lane&15, row = (lane>>4)*4 + reg ----
  const int r0 = m0 + wm * 128 + (l >> 4) * 4;
  const int c0 = n0 + wn * 64 + (l & 15);
  if (BF16_OUT) {
    bf16_t* C = (bf16_t*)Cout;
#pragma unroll
    for (int i = 0; i < 8; ++i)
#pragma unroll
      for (int j = 0; j < 4; ++j)
#pragma unroll
        for (int r = 0; r < 4; ++r)
          C[(size_t)(r0 + i * 16 + r) * N + (c0 + j * 16)] = (bf16_t)acc[i][j][r];
  } else {
    float* C = (float*)Cout;
#pragma unroll
    for (int i = 0; i < 8; ++i)
#pragma unroll
      for (int j = 0; j < 4; ++j)
#pragma unroll
        for (int r = 0; r < 4; ++r)
          C[(size_t)(r0 + i * 16 + r) * N + (c0 + j * 16)] =
              acc[i][j][r] + bias[c0 + j * 16];
  }
}

// ---------------- per-token head-attention ----------------
__global__ __launch_bounds__(256)
void attn_heads(const bf16_t* __restrict__ qkv, bf16_t* __restrict__ out) {
  __shared__ float s[4][3072];
  const int w = threadIdx.x >> 6, l = threadIdx.x & 63;
  const size_t t = (size_t)blockIdx.x * 4 + w;
  const bf16_t* src = qkv + t * 3072;
#pragma unroll
  for (int i = 0; i < 6; ++i) {
    int f = (i * 64 + l) * 8;
    bf16x8 v = *reinterpret_cast<const bf16x8*>(&src[f]);
#pragma unroll
    for (int jj = 0; jj < 8; ++jj) s[w][f + jj] = (float)v[jj];
  }
  __syncthreads();

  const int h = l >> 2, ss = l & 3;
  float qr[16];
  const float* qb = &s[w][h * 192 + ss * 16];
#pragma unroll
  for (int d = 0; d < 16; ++d) qr[d] = qb[d];

  float sc[16];
#pragma unroll
  for (int g = 0; g < 16; ++g) {
    const float* kk = &s[w][g * 192 + 64 + ss * 16];
    float p = 0.f;
#pragma unroll
    for (int d = 0; d < 16; ++d) p += qr[d] * kk[d];
    p += __shfl_xor(p, 1);
    p += __shfl_xor(p, 2);
    sc[g] = p * 0.125f;
  }
  float m = sc[0];
#pragma unroll
  for (int g = 1; g < 16; ++g) m = fmaxf(m, sc[g]);
  float sum = 0.f;
#pragma unroll
  for (int g = 0; g < 16; ++g) { sc[g] = __expf(sc[g] - m); sum += sc[g]; }
  float inv = 1.f / sum;

  float o[16] = {};
#pragma unroll
  for (int g = 0; g < 16; ++g) {
    float a = sc[g] * inv;
    const float* vv = &s[w][g * 192 + 128 + ss * 16];
#pragma unroll
    for (int d = 0; d < 16; ++d) o[d] += a * vv[d];
  }
  union { bf16_t b[16]; uint4 u[2]; } pk;
#pragma unroll
  for (int d = 0; d < 16; ++d) pk.b[d] = (bf16_t)o[d];
  uint4* dst = reinterpret_cast<uint4*>(out + t * 1024 + h * 64 + ss * 16);
  dst[0] = pk.u[0];
  dst[1] = pk.u[1];
}

// ---------------- launch ----------------
extern "C" void kernel_launch(void* const* d_in, const int* in_sizes, int n_in,
                              void* d_out, int out_size, void* d_ws, size_t ws_size,
                              hipStream_t stream) {
  const float* x     = (const float*)d_in[0];  // [8,2048,1024]
  const float* Wqkv  = (const float*)d_in[1];  // [3072,1024]
  const float* Wproj = (const float*)d_in[2];  // [1024,1024]
  const float* bproj = (const float*)d_in[3];  // [1024]
  float* out = (float*)d_out;

  const int M = 8 * 2048;   // 16384 tokens -> 64 bx blocks of 256
  const int DM = 1024;
  const int F = 3072;

  char* ws = (char*)d_ws;
  bf16_t* xb     = (bf16_t*)ws;  ws += (size_t)M * DM * 2;
  bf16_t* wqkvb  = (bf16_t*)ws;  ws += (size_t)F * DM * 2;
  bf16_t* wprojb = (bf16_t*)ws;  ws += (size_t)DM * DM * 2;
  bf16_t* qkvb   = (bf16_t*)ws;  ws += (size_t)M * F * 2;
  bf16_t* attnb  = (bf16_t*)ws;

  cast3_f32_bf16<<<2048, 256, 0, stream>>>(x, xb, M * DM / 4,
                                           Wqkv, wqkvb, F * DM / 4,
                                           Wproj, wprojb, DM * DM / 4);

  // GEMM1: [16384,1024] x [3072,1024]^T -> bf16 [16384,3072]
  gemm_3b<true><<<(M / 256) * (F / 128), 256, 0, stream>>>(
      xb, wqkvb, (void*)qkvb, nullptr, F);

  attn_heads<<<M / 4, 256, 0, stream>>>(qkvb, attnb);

  // GEMM2: [16384,1024] x [1024,1024]^T -> f32 [16384,1024] + bias
  gemm_3b<false><<<(M / 256) * (DM / 128), 256, 0, stream>>>(
      attnb, wprojb, (void*)out, bproj, DM);
}

// Round 13
// 212.354 us; speedup vs baseline: 2.3229x; 1.0333x over previous
//
#include <hip/hip_runtime.h>
#include <stdint.h>

typedef __bf16 bf16_t;
typedef __bf16 bf16x8 __attribute__((ext_vector_type(8)));
typedef float f32x4 __attribute__((ext_vector_type(4)));

// async global->LDS, 16B per lane; HW dest = wave-uniform base + lane*16
__device__ __forceinline__ void gload_lds16(const void* g, void* l) {
  __builtin_amdgcn_global_load_lds(
      (const __attribute__((address_space(1))) uint32_t*)g,
      (__attribute__((address_space(3))) uint32_t*)l, 16, 0, 0);
}

// ---------------- cast f32 -> bf16 (x only) ----------------
__global__ void cast_f32_bf16(const float* __restrict__ in,
                              bf16_t* __restrict__ out, int n4) {
  int i = blockIdx.x * blockDim.x + threadIdx.x;
  int stride = gridDim.x * blockDim.x;
  for (int idx = i; idx < n4; idx += stride) {
    float4 v = reinterpret_cast<const float4*>(in)[idx];
    union { bf16_t b[4]; uint2 u; } pk;
    pk.b[0] = (bf16_t)v.x; pk.b[1] = (bf16_t)v.y;
    pk.b[2] = (bf16_t)v.z; pk.b[3] = (bf16_t)v.w;
    reinterpret_cast<uint2*>(out)[idx] = pk.u;
  }
}

// ---- W f32 [N][K] -> W' bf16 MFMA-frag blocks: block (n16,k32) = 1KB,
// lane l holds col n16*16+(l&15), k k32*32+(l>>4)*8.. (16B), stored lane-linear
// so a wave frag-load = one coalesced 1KB global_load_dwordx4.
__global__ void wtransform(const float* __restrict__ W, bf16_t* __restrict__ Wp,
                           int N, int K) {
  int wid = (blockIdx.x * blockDim.x + threadIdx.x) >> 6;
  int l = threadIdx.x & 63;
  int nb = (N / 16) * (K / 32);
  if (wid >= nb) return;
  int n16 = wid / (K / 32), k32 = wid % (K / 32);
  const float* src = W + (size_t)(n16 * 16 + (l & 15)) * K + k32 * 32 + (l >> 4) * 8;
  float4 v0 = *reinterpret_cast<const float4*>(src);
  float4 v1 = *reinterpret_cast<const float4*>(src + 4);
  union { bf16_t b[8]; uint4 u; } pk;
  pk.b[0] = (bf16_t)v0.x; pk.b[1] = (bf16_t)v0.y;
  pk.b[2] = (bf16_t)v0.z; pk.b[3] = (bf16_t)v0.w;
  pk.b[4] = (bf16_t)v1.x; pk.b[5] = (bf16_t)v1.y;
  pk.b[6] = (bf16_t)v1.z; pk.b[7] = (bf16_t)v1.w;
  *reinterpret_cast<uint4*>(Wp + (size_t)wid * 512 + l * 8) = pk.u;
}

// ---- B-direct GEMM: C[M][N] = A[M][K] * B[N][K]^T (+bias) ----
// BM=BN=256, BK=32, K=1024 (NT=32). 512 thr = 8 waves (2M x 4N), wave tile
// 128x64 = 8x4 frags 16x16x32 bf16. A via LDS (2-dbuf, 32KB, swizzled,
// 0-conflict r4 layout); B DIRECT from L2 in frag layout (4 coalesced 1KB
// loads/wave/tile, reg ping-pong) -> B off the LDS pipe, no B barriers.
// Per tile (ONE barrier): ST_A(t+1) 2 gload_lds | BLOAD(t+1) 4 glb loads |
//   RDA(t) 8 ds_read | 32 MFMA (compiler waits: lgkm for A, vmcnt for B) |
//   vmcnt(4) -> ST_A(t+1) landed (B(t+1) 4 still fly) | s_barrier.
// Budget/tile/CU: MFMA 1242cy || LDS ~715cy || VMEM B 64KB@L2 ~1200cy.
// Ring safety: Al[(t+1)&1] last read at t-1 (MFMA data-dep => reads done
// before t-1's barrier); writes issued after it, land pre-t's-barrier.
// Grid: XCD x owns bx slab [x*8,x*8+8) (A-slab 4MB = its L2), bx-fast.
template <bool BF16_OUT>
__global__ __launch_bounds__(512, 2)
void gemm_bd(const bf16_t* __restrict__ A, const bf16_t* __restrict__ Bp,
             void* __restrict__ Cout, const float* __restrict__ bias, int N) {
  constexpr int K = 1024, NT = 32;
  __shared__ bf16_t Al[2][256 * 32];  // 2 x 16KB

  const int tid = threadIdx.x;
  const int l = tid & 63, w = tid >> 6;
  const int wm = w >> 2, wn = w & 3;

  const int bid = blockIdx.x;
  const int xcd = bid & 7, idx = bid >> 3;
  const int bx = xcd * 8 + (idx & 7);  // nbx = 64 (M = 16384)
  const int by = idx >> 3;
  const int m0 = bx * 256, n0 = by * 256;

  // A staging (512 thr, 8KB/issue = 128 rows): thread t: row = t>>2,
  // lds chunk = t&3, global chunk = (t&3)^((row>>1)&3) = (t&3)^((t>>3)&3)
  const int ra = tid >> 2;
  const int ca = ((tid & 3) ^ ((tid >> 3) & 3)) * 8;
  const bf16_t* pA0 = A + (size_t)(m0 + ra) * K + ca;
  const bf16_t* pA1 = A + (size_t)(m0 + 128 + ra) * K + ca;
  const int wb = w * 512;

#define ST_A(t_, s_) do { const int kt_ = (t_) * 32;   \
    gload_lds16(pA0 + kt_, &Al[s_][wb]);               \
    gload_lds16(pA1 + kt_, &Al[s_][4096 + wb]); } while (0)

  // A frag reads: row = wm*128 + i*16 + (l&15) -> (row>>1)&3 = (l>>1)&3
  const int abase = (wm * 128 + (l & 15)) * 32;
  const int ck = ((l >> 4) ^ ((l >> 1) & 3)) * 8;

#define RDA(s_) do { const bf16_t* As_ = Al[s_];                                  \
    _Pragma("unroll") for (int i = 0; i < 8; ++i)                                 \
      af[i] = *reinterpret_cast<const bf16x8*>(&As_[abase + i * 512 + ck]);       \
  } while (0)

  // B' direct: frag j of tile t at Bw + j*16384 + t*512 (elems), lane-linear
  const bf16_t* Bw = Bp + ((size_t)(n0 / 16 + wn * 4) * 32) * 512 + (size_t)l * 8;

#define BLOAD(dst, t_) do {                                                       \
    _Pragma("unroll") for (int j = 0; j < 4; ++j)                                 \
      dst[j] = *reinterpret_cast<const bf16x8*>(Bw + j * 16384 + (t_) * 512);     \
  } while (0)

#define MM32(bf_)                                                                 \
    __builtin_amdgcn_s_setprio(1);                                                \
    _Pragma("unroll") for (int i = 0; i < 8; ++i)                                 \
    _Pragma("unroll") for (int j = 0; j < 4; ++j)                                 \
      acc[i][j] = __builtin_amdgcn_mfma_f32_16x16x32_bf16(                        \
          af[i], bf_[j], acc[i][j], 0, 0, 0);                                     \
    __builtin_amdgcn_s_setprio(0);

#define BARF() do { asm volatile("" ::: "memory");  \
    __builtin_amdgcn_s_barrier();                   \
    asm volatile("" ::: "memory"); } while (0)

#define TILE(t_, BC, BN_) do {                                                    \
    if ((t_) + 1 < NT) { ST_A((t_) + 1, ((t_) + 1) & 1); BLOAD(BN_, (t_) + 1); }  \
    RDA((t_) & 1);                                                                \
    MM32(BC);                                                                     \
    if ((t_) + 1 < NT) {                                                          \
      asm volatile("s_waitcnt vmcnt(4)" ::: "memory");                            \
      BARF();                                                                     \
    }                                                                             \
  } while (0)

  f32x4 acc[8][4] = {};
  bf16x8 af[8], bcur[4], bnext[4];

  // prologue: stage tile0 (2 gloads) + B(0) (4 loads); drain the 2 stages
  ST_A(0, 0);
  BLOAD(bcur, 0);
  asm volatile("s_waitcnt vmcnt(4)" ::: "memory");
  BARF();

  for (int t = 0; t < NT; t += 2) {
    TILE(t, bcur, bnext);
    TILE(t + 1, bnext, bcur);
  }
#undef ST_A
#undef RDA
#undef BLOAD
#undef MM32
#undef BARF
#undef TILE

  // ---- epilogue: C/D layout col = lane&15, row = (lane>>4)*4 + reg ----
  const int r0 = m0 + wm * 128 + (l >> 4) * 4;
  const int c0 = n0 + wn * 64 + (l & 15);
  if (BF16_OUT) {
    bf16_t* C = (bf16_t*)Cout;
#pragma unroll
    for (int i = 0; i < 8; ++i)
#pragma unroll
      for (int j = 0; j < 4; ++j)
#pragma unroll
        for (int r = 0; r < 4; ++r)
          C[(size_t)(r0 + i * 16 + r) * N + (c0 + j * 16)] = (bf16_t)acc[i][j][r];
  } else {
    float* C = (float*)Cout;
#pragma unroll
    for (int i = 0; i < 8; ++i)
#pragma unroll
      for (int j = 0; j < 4; ++j)
#pragma unroll
        for (int r = 0; r < 4; ++r)
          C[(size_t)(r0 + i * 16 + r) * N + (c0 + j * 16)] =
              acc[i][j][r] + bias[c0 + j * 16];
  }
}

// ---------------- per-token head-attention ----------------
__global__ __launch_bounds__(256)
void attn_heads(const bf16_t* __restrict__ qkv, bf16_t* __restrict__ out) {
  __shared__ float s[4][3072];
  const int w = threadIdx.x >> 6, l = threadIdx.x & 63;
  const size_t t = (size_t)blockIdx.x * 4 + w;
  const bf16_t* src = qkv + t * 3072;
#pragma unroll
  for (int i = 0; i < 6; ++i) {
    int f = (i * 64 + l) * 8;
    bf16x8 v = *reinterpret_cast<const bf16x8*>(&src[f]);
#pragma unroll
    for (int jj = 0; jj < 8; ++jj) s[w][f + jj] = (float)v[jj];
  }
  __syncthreads();

  const int h = l >> 2, ss = l & 3;
  float qr[16];
  const float* qb = &s[w][h * 192 + ss * 16];
#pragma unroll
  for (int d = 0; d < 16; ++d) qr[d] = qb[d];

  float sc[16];
#pragma unroll
  for (int g = 0; g < 16; ++g) {
    const float* kk = &s[w][g * 192 + 64 + ss * 16];
    float p = 0.f;
#pragma unroll
    for (int d = 0; d < 16; ++d) p += qr[d] * kk[d];
    p += __shfl_xor(p, 1);
    p += __shfl_xor(p, 2);
    sc[g] = p * 0.125f;
  }
  float m = sc[0];
#pragma unroll
  for (int g = 1; g < 16; ++g) m = fmaxf(m, sc[g]);
  float sum = 0.f;
#pragma unroll
  for (int g = 0; g < 16; ++g) { sc[g] = __expf(sc[g] - m); sum += sc[g]; }
  float inv = 1.f / sum;

  float o[16] = {};
#pragma unroll
  for (int g = 0; g < 16; ++g) {
    float a = sc[g] * inv;
    const float* vv = &s[w][g * 192 + 128 + ss * 16];
#pragma unroll
    for (int d = 0; d < 16; ++d) o[d] += a * vv[d];
  }
  union { bf16_t b[16]; uint4 u[2]; } pk;
#pragma unroll
  for (int d = 0; d < 16; ++d) pk.b[d] = (bf16_t)o[d];
  uint4* dst = reinterpret_cast<uint4*>(out + t * 1024 + h * 64 + ss * 16);
  dst[0] = pk.u[0];
  dst[1] = pk.u[1];
}

// ---------------- launch ----------------
extern "C" void kernel_launch(void* const* d_in, const int* in_sizes, int n_in,
                              void* d_out, int out_size, void* d_ws, size_t ws_size,
                              hipStream_t stream) {
  const float* x     = (const float*)d_in[0];  // [8,2048,1024]
  const float* Wqkv  = (const float*)d_in[1];  // [3072,1024]
  const float* Wproj = (const float*)d_in[2];  // [1024,1024]
  const float* bproj = (const float*)d_in[3];  // [1024]
  float* out = (float*)d_out;

  const int M = 8 * 2048;   // 16384 tokens -> 64 bx blocks of 256
  const int DM = 1024;
  const int F = 3072;

  char* ws = (char*)d_ws;
  bf16_t* xb     = (bf16_t*)ws;  ws += (size_t)M * DM * 2;   // 33.6 MB
  bf16_t* wqkvp  = (bf16_t*)ws;  ws += (size_t)F * DM * 2;   //  6.3 MB (frag layout)
  bf16_t* wprojp = (bf16_t*)ws;  ws += (size_t)DM * DM * 2;  //  2.1 MB (frag layout)
  bf16_t* qkvb   = (bf16_t*)ws;  ws += (size_t)M * F * 2;    // 100.7 MB
  bf16_t* attnb  = (bf16_t*)ws;                               // 33.6 MB

  cast_f32_bf16<<<2048, 256, 0, stream>>>(x, xb, M * DM / 4);
  // W transforms: one wave per 1KB frag block
  wtransform<<<(F / 16) * (DM / 32) / 4, 256, 0, stream>>>(Wqkv, wqkvp, F, DM);
  wtransform<<<(DM / 16) * (DM / 32) / 4, 256, 0, stream>>>(Wproj, wprojp, DM, DM);

  // GEMM1: [16384,1024] x [3072,1024]^T -> bf16 [16384,3072]
  gemm_bd<true><<<(M / 256) * (F / 256), 512, 0, stream>>>(
      xb, wqkvp, (void*)qkvb, nullptr, F);

  attn_heads<<<M / 4, 256, 0, stream>>>(qkvb, attnb);

  // GEMM2: [16384,1024] x [1024,1024]^T -> f32 [16384,1024] + bias
  gemm_bd<false><<<(M / 256) * (DM / 256), 512, 0, stream>>>(
      attnb, wprojp, (void*)out, bproj, DM);
}